// Round 1
// baseline (651.995 us; speedup 1.0000x reference)
//
#include <hip/hip_runtime.h>
#include <hip/hip_bf16.h>
#include <math.h>

#define NNODES 100000
#define NEDGES 400000
#define INDIM  128
#define HDIM   256
#define MAXDEG 32

#define BM 128
#define BN 128
#define BK 64

typedef __attribute__((ext_vector_type(8))) short short8;
typedef __attribute__((ext_vector_type(4))) float f32x4;

__device__ __forceinline__ float bf2f(unsigned short u) {
    union { unsigned int i; float f; } v; v.i = ((unsigned int)u) << 16; return v.f;
}
__device__ __forceinline__ unsigned short f2bf(float f) {
    union { float f; unsigned int i; } v; v.f = f;
    unsigned int r = v.i + 0x7fffu + ((v.i >> 16) & 1u);   // RNE
    return (unsigned short)(r >> 16);
}

__device__ __forceinline__ void async_load16(const void* g, void* l) {
    __builtin_amdgcn_global_load_lds(
        (const __attribute__((address_space(1))) unsigned int*)g,
        (__attribute__((address_space(3))) unsigned int*)l,
        16, 0, 0);
}

// ---------------- edge-list build (scatter -> gather inversion) --------------
__global__ void build_elist(const int* __restrict__ ei, int* __restrict__ cnt,
                            int* __restrict__ elist) {
    int e = blockIdx.x * 256 + threadIdx.x;
    if (e < NEDGES) {
        int d = ei[NEDGES + e];            // dst
        int s = ei[e];                     // src
        int pos = atomicAdd(&cnt[d], 1);
        if (pos < MAXDEG) elist[d * MAXDEG + pos] = s;
    }
}

// ---------------- converts -------------------------------------------------
__global__ void convert_x(const float* __restrict__ x, unsigned short* __restrict__ xb) {
    int i = blockIdx.x * 256 + threadIdx.x;          // quad index
    const int total = NNODES * INDIM / 4;
    if (i < total) {
        float4 v = ((const float4*)x)[i];
        ushort4 o; o.x = f2bf(v.x); o.y = f2bf(v.y); o.z = f2bf(v.z); o.w = f2bf(v.w);
        ((ushort4*)xb)[i] = o;
    }
}

// B[n][k] = Wr[n][k] for k<K else Ws[n][k-K]   (HDIM x 2K, row-major, bf16)
__global__ void convert_w(const float* __restrict__ Wr, const float* __restrict__ Ws,
                          unsigned short* __restrict__ B, int K) {
    int idx = blockIdx.x * 256 + threadIdx.x;
    int tot = HDIM * 2 * K;
    if (idx < tot) {
        int n = idx / (2 * K);
        int k = idx - n * 2 * K;
        float v = (k < K) ? Wr[n * K + k] : Ws[n * K + (k - K)];
        B[idx] = f2bf(v);
    }
}

// ---------------- gathers (agg = sum over incoming edges) -------------------
__global__ void gather_f32(const float* __restrict__ x, const int* __restrict__ cnt,
                           const int* __restrict__ elist, unsigned short* __restrict__ agg) {
    int wid  = (blockIdx.x * blockDim.x + threadIdx.x) >> 6;
    int lane = threadIdx.x & 63;
    if (wid >= NNODES) return;
    int c = cnt[wid]; if (c > MAXDEG) c = MAXDEG;
    const int* el = elist + wid * MAXDEG;
    float a0 = 0.f, a1 = 0.f;
    for (int j = 0; j < c; j++) {
        int s = el[j];
        float2 v = ((const float2*)(x + (size_t)s * INDIM))[lane];
        a0 += v.x; a1 += v.y;
    }
    ushort2 o; o.x = f2bf(a0); o.y = f2bf(a1);
    ((ushort2*)(agg + (size_t)wid * INDIM))[lane] = o;
}

__global__ void gather_bf16(const unsigned short* __restrict__ h, const int* __restrict__ cnt,
                            const int* __restrict__ elist, unsigned short* __restrict__ agg) {
    int wid  = (blockIdx.x * blockDim.x + threadIdx.x) >> 6;
    int lane = threadIdx.x & 63;
    if (wid >= NNODES) return;
    int c = cnt[wid]; if (c > MAXDEG) c = MAXDEG;
    const int* el = elist + wid * MAXDEG;
    float a0 = 0.f, a1 = 0.f, a2 = 0.f, a3 = 0.f;
    for (int j = 0; j < c; j++) {
        int s = el[j];
        ushort4 v = ((const ushort4*)(h + (size_t)s * HDIM))[lane];
        a0 += bf2f(v.x); a1 += bf2f(v.y); a2 += bf2f(v.z); a3 += bf2f(v.w);
    }
    ushort4 o; o.x = f2bf(a0); o.y = f2bf(a1); o.z = f2bf(a2); o.w = f2bf(a3);
    ((ushort4*)(agg + (size_t)wid * HDIM))[lane] = o;
}

// ---------------- fused dual-GEMM + bias + relu -----------------------------
// C[m][n] = sum_k A1[m][k]*W_r[n][k] + sum_k A2[m][k]*W_s[n][k]  (+bias, relu)
// B buffer is [n][k] over k_tot=2K (W_r then W_s).
// MODE 0: write bf16 h-out (N x 256). MODE 1: write fp32 xs + x1/x2 split.
template<int MODE>
__global__ __launch_bounds__(256)
void gemm_kernel(const unsigned short* __restrict__ A1, const unsigned short* __restrict__ A2,
                 int K, const unsigned short* __restrict__ B, const float* __restrict__ bias,
                 unsigned short* __restrict__ hout,
                 float* __restrict__ xs, float* __restrict__ x1o, float* __restrict__ x2o) {
    __shared__ unsigned short Ash[BM * BK];
    __shared__ unsigned short Bsh[BN * BK];

    const int tid  = threadIdx.x;
    const int lane = tid & 63;
    const int wave = tid >> 6;
    const int wm = wave >> 1, wn = wave & 1;
    const int m0 = blockIdx.x * BM;
    const int n0 = blockIdx.y * BN;
    const int Ktot = 2 * K;

    f32x4 acc[4][4];
    for (int i = 0; i < 4; i++)
        for (int j = 0; j < 4; j++)
            acc[i][j] = (f32x4){0.f, 0.f, 0.f, 0.f};

    for (int k0 = 0; k0 < Ktot; k0 += BK) {
        const unsigned short* Abase; int koff;
        if (k0 < K) { Abase = A1; koff = k0; } else { Abase = A2; koff = k0 - K; }

        // stage A: 128 rows x 64 cols bf16, 16B segments, xor-swizzled
        #pragma unroll
        for (int it = 0; it < 4; it++) {
            int idx = it * 256 + tid;
            int row = idx >> 3, seg = idx & 7;
            int gseg = seg ^ (row & 7);
            int grow = m0 + row; if (grow >= NNODES) grow = NNODES - 1;
            async_load16(Abase + (size_t)grow * K + koff + gseg * 8, &Ash[idx * 8]);
        }
        // stage B: rows are output cols n (always < 256)
        #pragma unroll
        for (int it = 0; it < 4; it++) {
            int idx = it * 256 + tid;
            int row = idx >> 3, seg = idx & 7;
            int gseg = seg ^ (row & 7);
            int grow = n0 + row;
            async_load16(B + (size_t)grow * Ktot + k0 + gseg * 8, &Bsh[idx * 8]);
        }
        __syncthreads();

        #pragma unroll
        for (int half = 0; half < 2; half++) {
            short8 af[4], bfr[4];
            #pragma unroll
            for (int mt = 0; mt < 4; mt++) {
                int ml  = wm * 64 + mt * 16 + (lane & 15);
                int seg = half * 4 + (lane >> 4);
                int ps  = seg ^ (ml & 7);
                af[mt] = *(const short8*)&Ash[ml * BK + ps * 8];
            }
            #pragma unroll
            for (int nt = 0; nt < 4; nt++) {
                int nl  = wn * 64 + nt * 16 + (lane & 15);
                int seg = half * 4 + (lane >> 4);
                int ps  = seg ^ (nl & 7);
                bfr[nt] = *(const short8*)&Bsh[nl * BK + ps * 8];
            }
            #pragma unroll
            for (int mt = 0; mt < 4; mt++)
                #pragma unroll
                for (int nt = 0; nt < 4; nt++)
                    acc[mt][nt] = __builtin_amdgcn_mfma_f32_16x16x32_bf16(
                        af[mt], bfr[nt], acc[mt][nt], 0, 0, 0);
        }
        __syncthreads();
    }

    // epilogue: C/D layout col=lane&15, row=(lane>>4)*4+reg
    #pragma unroll
    for (int mt = 0; mt < 4; mt++) {
        int rbase = m0 + wm * 64 + mt * 16 + (lane >> 4) * 4;
        #pragma unroll
        for (int nt = 0; nt < 4; nt++) {
            int gc = n0 + wn * 64 + nt * 16 + (lane & 15);
            float bv = bias[gc];
            #pragma unroll
            for (int r = 0; r < 4; r++) {
                int grow = rbase + r;
                if (grow >= NNODES) continue;
                float v = acc[mt][nt][r] + bv;
                v = v > 0.f ? v : 0.f;
                if (MODE == 0) {
                    hout[(size_t)grow * HDIM + gc] = f2bf(v);
                } else {
                    xs[(size_t)grow * HDIM + gc] = v;
                    int pr = grow >> 1;
                    if (grow & 1) x2o[(size_t)pr * HDIM + gc] = v;
                    else          x1o[(size_t)pr * HDIM + gc] = v;
                }
            }
        }
    }
}

// ---------------- head: y = sigmoid(relu(x1.Wsp1+b)*Wl0 + relu(x2.Wsp2+b)*Wl1 + bl)
__global__ void head_kernel(const float* __restrict__ h3, const float* __restrict__ Wsp1,
                            const float* __restrict__ bsp1, const float* __restrict__ Wsp2,
                            const float* __restrict__ bsp2, const float* __restrict__ Wl,
                            const float* __restrict__ bl, float* __restrict__ y) {
    int wid  = (blockIdx.x * blockDim.x + threadIdx.x) >> 6;
    int lane = threadIdx.x & 63;
    if (wid >= NNODES / 2) return;
    float4 a  = ((const float4*)(h3 + (size_t)(2 * wid) * HDIM))[lane];
    float4 w1 = ((const float4*)Wsp1)[lane];
    float4 c  = ((const float4*)(h3 + (size_t)(2 * wid + 1) * HDIM))[lane];
    float4 w2 = ((const float4*)Wsp2)[lane];
    float s1 = a.x * w1.x + a.y * w1.y + a.z * w1.z + a.w * w1.w;
    float s2 = c.x * w2.x + c.y * w2.y + c.z * w2.z + c.w * w2.w;
    #pragma unroll
    for (int off = 32; off; off >>= 1) {
        s1 += __shfl_down(s1, off);
        s2 += __shfl_down(s2, off);
    }
    if (lane == 0) {
        s1 += bsp1[0]; s2 += bsp2[0];
        s1 = s1 > 0.f ? s1 : 0.f;
        s2 = s2 > 0.f ? s2 : 0.f;
        float t = s1 * Wl[0] + s2 * Wl[1] + bl[0];
        y[wid] = 1.f / (1.f + expf(-t));
    }
}

extern "C" void kernel_launch(void* const* d_in, const int* in_sizes, int n_in,
                              void* d_out, int out_size, void* d_ws, size_t ws_size,
                              hipStream_t stream) {
    const float* x    = (const float*)d_in[0];
    const int*   ei   = (const int*)d_in[1];
    const float* Wr0  = (const float*)d_in[3];
    const float* br0  = (const float*)d_in[4];
    const float* Ws0  = (const float*)d_in[5];
    const float* Wr1  = (const float*)d_in[6];
    const float* br1  = (const float*)d_in[7];
    const float* Ws1  = (const float*)d_in[8];
    const float* Wr2  = (const float*)d_in[9];
    const float* br2  = (const float*)d_in[10];
    const float* Ws2  = (const float*)d_in[11];
    const float* Wsp1 = (const float*)d_in[12];
    const float* bsp1 = (const float*)d_in[13];
    const float* Wsp2 = (const float*)d_in[14];
    const float* bsp2 = (const float*)d_in[15];
    const float* Wl   = (const float*)d_in[16];
    const float* bl   = (const float*)d_in[17];

    char* ws = (char*)d_ws;
    size_t off = 0;
    auto alloc = [&](size_t bytes) -> void* {
        void* p = ws + off;
        off += (bytes + 255) & ~(size_t)255;
        return p;
    };
    int*            cnt   = (int*)alloc((size_t)NNODES * 4);
    int*            elist = (int*)alloc((size_t)NNODES * MAXDEG * 4);
    unsigned short* xb    = (unsigned short*)alloc((size_t)NNODES * INDIM * 2);
    unsigned short* aggb  = (unsigned short*)alloc((size_t)NNODES * HDIM * 2);
    unsigned short* hA    = (unsigned short*)alloc((size_t)NNODES * HDIM * 2);
    unsigned short* hB    = (unsigned short*)alloc((size_t)NNODES * HDIM * 2);
    unsigned short* B0    = (unsigned short*)alloc((size_t)HDIM * 2 * INDIM * 2);
    unsigned short* B1    = (unsigned short*)alloc((size_t)HDIM * 2 * HDIM * 2);
    unsigned short* B2    = (unsigned short*)alloc((size_t)HDIM * 2 * HDIM * 2);

    // d_out layout: y (50000) | xs (50000*512) | x1 (50000*256) | x2 (50000*256)
    float* y  = (float*)d_out;
    float* xs = y + 50000;
    float* x1 = xs + (size_t)50000 * 512;
    float* x2 = x1 + (size_t)50000 * 256;

    hipMemsetAsync(cnt, 0, (size_t)NNODES * 4, stream);
    build_elist<<<(NEDGES + 255) / 256, 256, 0, stream>>>(ei, cnt, elist);
    convert_x<<<(NNODES * INDIM / 4 + 255) / 256, 256, 0, stream>>>(x, xb);
    convert_w<<<(HDIM * 2 * INDIM + 255) / 256, 256, 0, stream>>>(Wr0, Ws0, B0, INDIM);
    convert_w<<<(HDIM * 2 * HDIM + 255) / 256, 256, 0, stream>>>(Wr1, Ws1, B1, HDIM);
    convert_w<<<(HDIM * 2 * HDIM + 255) / 256, 256, 0, stream>>>(Wr2, Ws2, B2, HDIM);

    dim3 gg((NNODES + BM - 1) / BM, HDIM / BN);
    int gather_blocks = (NNODES * 64 + 255) / 256;

    // layer 0: K=128
    gather_f32<<<gather_blocks, 256, 0, stream>>>(x, cnt, elist, aggb);
    gemm_kernel<0><<<gg, 256, 0, stream>>>(aggb, xb, INDIM, B0, br0, hA, nullptr, nullptr, nullptr);
    // layer 1: K=256
    gather_bf16<<<gather_blocks, 256, 0, stream>>>(hA, cnt, elist, aggb);
    gemm_kernel<0><<<gg, 256, 0, stream>>>(aggb, hA, HDIM, B1, br1, hB, nullptr, nullptr, nullptr);
    // layer 2: K=256, fp32 outputs straight into d_out (xs + x1/x2 split)
    gather_bf16<<<gather_blocks, 256, 0, stream>>>(hB, cnt, elist, aggb);
    gemm_kernel<1><<<gg, 256, 0, stream>>>(aggb, hB, HDIM, B2, br2, nullptr, xs, x1, x2);
    // head
    head_kernel<<<((NNODES / 2) * 64 + 255) / 256, 256, 0, stream>>>(
        xs, Wsp1, bsp1, Wsp2, bsp2, Wl, bl, y);
}

// Round 2
// 618.262 us; speedup vs baseline: 1.0546x; 1.0546x over previous
//
#include <hip/hip_runtime.h>
#include <hip/hip_bf16.h>
#include <math.h>

#define NNODES 100000
#define NEDGES 400000
#define INDIM  128
#define HDIM   256
#define MAXDEG 32

#define BM 128
#define BN 128
#define BK 64
#define MTILES 782            // ceil(NNODES/BM)
#define GEMM_BLOCKS 1568      // ceil(MTILES*2 / 16) * 16

typedef __attribute__((ext_vector_type(8))) short short8;
typedef __attribute__((ext_vector_type(8))) unsigned short ushort8v;
typedef __attribute__((ext_vector_type(4))) float f32x4;

__device__ __forceinline__ float bf2f(unsigned short u) {
    union { unsigned int i; float f; } v; v.i = ((unsigned int)u) << 16; return v.f;
}
__device__ __forceinline__ unsigned short f2bf(float f) {
    union { float f; unsigned int i; } v; v.f = f;
    unsigned int r = v.i + 0x7fffu + ((v.i >> 16) & 1u);   // RNE
    return (unsigned short)(r >> 16);
}

__device__ __forceinline__ void async_load16(const void* g, void* l) {
    __builtin_amdgcn_global_load_lds(
        (const __attribute__((address_space(1))) unsigned int*)g,
        (__attribute__((address_space(3))) unsigned int*)l,
        16, 0, 0);
}

// ---------------- edge-list build (scatter -> gather inversion) --------------
__global__ void build_elist(const int* __restrict__ ei, int* __restrict__ cnt,
                            int* __restrict__ elist) {
    int e = blockIdx.x * 256 + threadIdx.x;
    if (e < NEDGES) {
        int d = ei[NEDGES + e];            // dst
        int s = ei[e];                     // src
        int pos = atomicAdd(&cnt[d], 1);
        if (pos < MAXDEG) elist[d * MAXDEG + pos] = s;
    }
}

// ---------------- converts -------------------------------------------------
__global__ void convert_x(const float* __restrict__ x, unsigned short* __restrict__ xb) {
    int i = blockIdx.x * 256 + threadIdx.x;          // quad index
    const int total = NNODES * INDIM / 4;
    if (i < total) {
        float4 v = ((const float4*)x)[i];
        ushort4 o; o.x = f2bf(v.x); o.y = f2bf(v.y); o.z = f2bf(v.z); o.w = f2bf(v.w);
        ((ushort4*)xb)[i] = o;
    }
}

// B[n][k] = Wr[n][k] for k<K else Ws[n][k-K]   (HDIM x 2K, row-major, bf16)
__global__ void convert_w(const float* __restrict__ Wr, const float* __restrict__ Ws,
                          unsigned short* __restrict__ B, int K) {
    int idx = blockIdx.x * 256 + threadIdx.x;
    int tot = HDIM * 2 * K;
    if (idx < tot) {
        int n = idx / (2 * K);
        int k = idx - n * 2 * K;
        float v = (k < K) ? Wr[n * K + k] : Ws[n * K + (k - K)];
        B[idx] = f2bf(v);
    }
}

// ---------------- gathers: int4 edge load + concurrent row loads ------------
__global__ void gather_f32(const float* __restrict__ x, const int* __restrict__ cnt,
                           const int* __restrict__ elist, unsigned short* __restrict__ agg) {
    int wid  = (blockIdx.x * blockDim.x + threadIdx.x) >> 6;
    int lane = threadIdx.x & 63;
    if (wid >= NNODES) return;
    int c = cnt[wid]; if (c > MAXDEG) c = MAXDEG;
    const int4* el4 = (const int4*)(elist + wid * MAXDEG);
    float a0 = 0.f, a1 = 0.f;
    for (int j0 = 0; j0 < c; j0 += 4) {
        int4 e = el4[j0 >> 2];
        int rem = c - j0;
        float2 v0 = {0.f,0.f}, v1 = {0.f,0.f}, v2 = {0.f,0.f}, v3 = {0.f,0.f};
        v0 = ((const float2*)(x + (size_t)e.x * INDIM))[lane];
        if (rem > 1) v1 = ((const float2*)(x + (size_t)e.y * INDIM))[lane];
        if (rem > 2) v2 = ((const float2*)(x + (size_t)e.z * INDIM))[lane];
        if (rem > 3) v3 = ((const float2*)(x + (size_t)e.w * INDIM))[lane];
        a0 += v0.x + v1.x + v2.x + v3.x;
        a1 += v0.y + v1.y + v2.y + v3.y;
    }
    ushort2 o; o.x = f2bf(a0); o.y = f2bf(a1);
    ((ushort2*)(agg + (size_t)wid * INDIM))[lane] = o;
}

__global__ void gather_bf16(const unsigned short* __restrict__ h, const int* __restrict__ cnt,
                            const int* __restrict__ elist, unsigned short* __restrict__ agg) {
    int wid  = (blockIdx.x * blockDim.x + threadIdx.x) >> 6;
    int lane = threadIdx.x & 63;
    if (wid >= NNODES) return;
    int c = cnt[wid]; if (c > MAXDEG) c = MAXDEG;
    const int4* el4 = (const int4*)(elist + wid * MAXDEG);
    float a0 = 0.f, a1 = 0.f, a2 = 0.f, a3 = 0.f;
    for (int j0 = 0; j0 < c; j0 += 4) {
        int4 e = el4[j0 >> 2];
        int rem = c - j0;
        ushort4 v0 = {0,0,0,0}, v1 = {0,0,0,0}, v2 = {0,0,0,0}, v3 = {0,0,0,0};
        v0 = ((const ushort4*)(h + (size_t)e.x * HDIM))[lane];
        if (rem > 1) v1 = ((const ushort4*)(h + (size_t)e.y * HDIM))[lane];
        if (rem > 2) v2 = ((const ushort4*)(h + (size_t)e.z * HDIM))[lane];
        if (rem > 3) v3 = ((const ushort4*)(h + (size_t)e.w * HDIM))[lane];
        a0 += bf2f(v0.x) + bf2f(v1.x) + bf2f(v2.x) + bf2f(v3.x);
        a1 += bf2f(v0.y) + bf2f(v1.y) + bf2f(v2.y) + bf2f(v3.y);
        a2 += bf2f(v0.z) + bf2f(v1.z) + bf2f(v2.z) + bf2f(v3.z);
        a3 += bf2f(v0.w) + bf2f(v1.w) + bf2f(v2.w) + bf2f(v3.w);
    }
    ushort4 o; o.x = f2bf(a0); o.y = f2bf(a1); o.z = f2bf(a2); o.w = f2bf(a3);
    ((ushort4*)(agg + (size_t)wid * HDIM))[lane] = o;
}

// ---------------- fused dual-GEMM + bias + relu (+head partial in MODE 1) ---
// C[m][n] = sum_k A1[m][k]*Wr[n][k] + sum_k A2[m][k]*Ws[n][k]  (+bias, relu)
// B buffer is [n][k] over k_tot=2K.  1D swizzled grid: pair (x,y=0)/(x,y=1)
// dispatched 8 apart -> same XCD (round-robin heuristic) -> A re-read L2-hits.
// MODE 0: bf16 h-out.  MODE 1: fp32 xs + x1/x2 split + head dot partials.
template<int MODE>
__global__ __launch_bounds__(256)
void gemm_kernel(const unsigned short* __restrict__ A1, const unsigned short* __restrict__ A2,
                 int K, const unsigned short* __restrict__ B, const float* __restrict__ bias,
                 unsigned short* __restrict__ hout,
                 float* __restrict__ xs, float* __restrict__ x1o, float* __restrict__ x2o,
                 const float* __restrict__ Wsp1, const float* __restrict__ Wsp2,
                 float* __restrict__ spart) {
    __shared__ __align__(16) unsigned char smem[(BM * BK + BN * BK) * 2];
    unsigned short* Ash = (unsigned short*)smem;
    unsigned short* Bsh = Ash + BM * BK;

    // swizzled tile coords
    int u = blockIdx.x;
    int g = u >> 4, r = u & 15;
    int ny = (r >> 3) & 1;
    int mx = g * 8 + (r & 7);
    if (mx >= MTILES) return;

    const int tid  = threadIdx.x;
    const int lane = tid & 63;
    const int wave = tid >> 6;
    const int wm = wave >> 1, wn = wave & 1;
    const int m0 = mx * BM;
    const int n0 = ny * BN;
    const int Ktot = 2 * K;

    f32x4 acc[4][4];
    for (int i = 0; i < 4; i++)
        for (int j = 0; j < 4; j++)
            acc[i][j] = (f32x4){0.f, 0.f, 0.f, 0.f};

    for (int k0 = 0; k0 < Ktot; k0 += BK) {
        const unsigned short* Abase; int koff;
        if (k0 < K) { Abase = A1; koff = k0; } else { Abase = A2; koff = k0 - K; }

        #pragma unroll
        for (int it = 0; it < 4; it++) {
            int idx = it * 256 + tid;
            int row = idx >> 3, seg = idx & 7;
            int gseg = seg ^ (row & 7);
            int grow = m0 + row; if (grow >= NNODES) grow = NNODES - 1;
            async_load16(Abase + (size_t)grow * K + koff + gseg * 8, &Ash[idx * 8]);
        }
        #pragma unroll
        for (int it = 0; it < 4; it++) {
            int idx = it * 256 + tid;
            int row = idx >> 3, seg = idx & 7;
            int gseg = seg ^ (row & 7);
            int grow = n0 + row;
            async_load16(B + (size_t)grow * Ktot + k0 + gseg * 8, &Bsh[idx * 8]);
        }
        __syncthreads();

        #pragma unroll
        for (int half = 0; half < 2; half++) {
            short8 af[4], bfr[4];
            #pragma unroll
            for (int mt = 0; mt < 4; mt++) {
                int ml  = wm * 64 + mt * 16 + (lane & 15);
                int seg = half * 4 + (lane >> 4);
                int ps  = seg ^ (ml & 7);
                af[mt] = *(const short8*)&Ash[ml * BK + ps * 8];
            }
            #pragma unroll
            for (int nt = 0; nt < 4; nt++) {
                int nl  = wn * 64 + nt * 16 + (lane & 15);
                int seg = half * 4 + (lane >> 4);
                int ps  = seg ^ (nl & 7);
                bfr[nt] = *(const short8*)&Bsh[nl * BK + ps * 8];
            }
            #pragma unroll
            for (int mt = 0; mt < 4; mt++)
                #pragma unroll
                for (int nt = 0; nt < 4; nt++)
                    acc[mt][nt] = __builtin_amdgcn_mfma_f32_16x16x32_bf16(
                        af[mt], bfr[nt], acc[mt][nt], 0, 0, 0);
        }
        __syncthreads();
    }

    // ---- epilogue via LDS bounce: wide coalesced stores ----
    // bounce layout per wave: 16 rows x 64 cols fp32, row stride 68 (2-way banks)
    float* bounce = (float*)smem;
    float* wb = bounce + wave * (16 * 68);
    const int q    = lane & 3;       // col segment (16 floats each) in read phase
    const int rrow = lane >> 2;      // row 0..15 in read phase

    #pragma unroll
    for (int mt = 0; mt < 4; mt++) {
        __syncthreads();
        #pragma unroll
        for (int nt = 0; nt < 4; nt++)
            #pragma unroll
            for (int rr = 0; rr < 4; rr++)
                wb[((lane >> 4) * 4 + rr) * 68 + nt * 16 + (lane & 15)] = acc[mt][nt][rr];
        __syncthreads();

        int grow = m0 + wm * 64 + mt * 16 + rrow;
        int gc   = n0 + wn * 64 + q * 16;
        float4 v[4];
        #pragma unroll
        for (int s = 0; s < 4; s++)
            v[s] = ((const float4*)(wb + rrow * 68 + q * 16))[s];

        if (grow < NNODES) {
            const float4* bv = (const float4*)(bias + gc);
            #pragma unroll
            for (int s = 0; s < 4; s++) {
                float4 b4 = bv[s];
                v[s].x = fmaxf(v[s].x + b4.x, 0.f);
                v[s].y = fmaxf(v[s].y + b4.y, 0.f);
                v[s].z = fmaxf(v[s].z + b4.z, 0.f);
                v[s].w = fmaxf(v[s].w + b4.w, 0.f);
            }
            if (MODE == 0) {
                ushort8v o0, o1;
                o0[0]=f2bf(v[0].x); o0[1]=f2bf(v[0].y); o0[2]=f2bf(v[0].z); o0[3]=f2bf(v[0].w);
                o0[4]=f2bf(v[1].x); o0[5]=f2bf(v[1].y); o0[6]=f2bf(v[1].z); o0[7]=f2bf(v[1].w);
                o1[0]=f2bf(v[2].x); o1[1]=f2bf(v[2].y); o1[2]=f2bf(v[2].z); o1[3]=f2bf(v[2].w);
                o1[4]=f2bf(v[3].x); o1[5]=f2bf(v[3].y); o1[6]=f2bf(v[3].z); o1[7]=f2bf(v[3].w);
                ushort8v* dst = (ushort8v*)(hout + (size_t)grow * HDIM + gc);
                dst[0] = o0; dst[1] = o1;
            } else {
                float4* xsp = (float4*)(xs + (size_t)grow * HDIM + gc);
                #pragma unroll
                for (int s = 0; s < 4; s++) xsp[s] = v[s];
                float* xo = (grow & 1) ? x2o : x1o;
                float4* xop = (float4*)(xo + (size_t)(grow >> 1) * HDIM + gc);
                #pragma unroll
                for (int s = 0; s < 4; s++) xop[s] = v[s];
                // head partial: dot(row, Wsp1|Wsp2) over this 64-col slice
                const float* wsp = (grow & 1) ? Wsp2 : Wsp1;
                const float4* wv = (const float4*)(wsp + gc);
                float p = 0.f;
                #pragma unroll
                for (int s = 0; s < 4; s++) {
                    float4 w4 = wv[s];
                    p += v[s].x * w4.x + v[s].y * w4.y + v[s].z * w4.z + v[s].w * w4.w;
                }
                p += __shfl_xor(p, 1);
                p += __shfl_xor(p, 2);
                if (q == 0) atomicAdd(&spart[grow], p);
            }
        }
    }
}

// ---------------- head finalize: 400 KB read instead of 102 MB --------------
__global__ void finalize_kernel(const float* __restrict__ spart, const float* __restrict__ bsp1,
                                const float* __restrict__ bsp2, const float* __restrict__ Wl,
                                const float* __restrict__ bl, float* __restrict__ y) {
    int p = blockIdx.x * 256 + threadIdx.x;
    if (p < NNODES / 2) {
        float s1 = spart[2 * p]     + bsp1[0]; s1 = s1 > 0.f ? s1 : 0.f;
        float s2 = spart[2 * p + 1] + bsp2[0]; s2 = s2 > 0.f ? s2 : 0.f;
        float t = s1 * Wl[0] + s2 * Wl[1] + bl[0];
        y[p] = 1.f / (1.f + expf(-t));
    }
}

extern "C" void kernel_launch(void* const* d_in, const int* in_sizes, int n_in,
                              void* d_out, int out_size, void* d_ws, size_t ws_size,
                              hipStream_t stream) {
    const float* x    = (const float*)d_in[0];
    const int*   ei   = (const int*)d_in[1];
    const float* Wr0  = (const float*)d_in[3];
    const float* br0  = (const float*)d_in[4];
    const float* Ws0  = (const float*)d_in[5];
    const float* Wr1  = (const float*)d_in[6];
    const float* br1  = (const float*)d_in[7];
    const float* Ws1  = (const float*)d_in[8];
    const float* Wr2  = (const float*)d_in[9];
    const float* br2  = (const float*)d_in[10];
    const float* Ws2  = (const float*)d_in[11];
    const float* Wsp1 = (const float*)d_in[12];
    const float* bsp1 = (const float*)d_in[13];
    const float* Wsp2 = (const float*)d_in[14];
    const float* bsp2 = (const float*)d_in[15];
    const float* Wl   = (const float*)d_in[16];
    const float* bl   = (const float*)d_in[17];

    char* ws = (char*)d_ws;
    size_t off = 0;
    auto alloc = [&](size_t bytes) -> void* {
        void* p = ws + off;
        off += (bytes + 255) & ~(size_t)255;
        return p;
    };
    int*            cnt   = (int*)alloc((size_t)NNODES * 4);          // zeroed
    float*          spart = (float*)alloc((size_t)NNODES * 4);        // zeroed (adjacent)
    size_t zero_bytes = off;
    int*            elist = (int*)alloc((size_t)NNODES * MAXDEG * 4);
    unsigned short* xb    = (unsigned short*)alloc((size_t)NNODES * INDIM * 2);
    unsigned short* aggb  = (unsigned short*)alloc((size_t)NNODES * HDIM * 2);
    unsigned short* hA    = (unsigned short*)alloc((size_t)NNODES * HDIM * 2);
    unsigned short* hB    = (unsigned short*)alloc((size_t)NNODES * HDIM * 2);
    unsigned short* B0    = (unsigned short*)alloc((size_t)HDIM * 2 * INDIM * 2);
    unsigned short* B1    = (unsigned short*)alloc((size_t)HDIM * 2 * HDIM * 2);
    unsigned short* B2    = (unsigned short*)alloc((size_t)HDIM * 2 * HDIM * 2);

    // d_out layout: y (50000) | xs (50000*512) | x1 (50000*256) | x2 (50000*256)
    float* y  = (float*)d_out;
    float* xs = y + 50000;
    float* x1 = xs + (size_t)50000 * 512;
    float* x2 = x1 + (size_t)50000 * 256;

    hipMemsetAsync(ws, 0, zero_bytes, stream);   // cnt + spart in one memset
    build_elist<<<(NEDGES + 255) / 256, 256, 0, stream>>>(ei, cnt, elist);
    convert_x<<<(NNODES * INDIM / 4 + 255) / 256, 256, 0, stream>>>(x, xb);
    convert_w<<<(HDIM * 2 * INDIM + 255) / 256, 256, 0, stream>>>(Wr0, Ws0, B0, INDIM);
    convert_w<<<(HDIM * 2 * HDIM + 255) / 256, 256, 0, stream>>>(Wr1, Ws1, B1, HDIM);
    convert_w<<<(HDIM * 2 * HDIM + 255) / 256, 256, 0, stream>>>(Wr2, Ws2, B2, HDIM);

    int gather_blocks = (NNODES * 64 + 255) / 256;

    // layer 0: K=128
    gather_f32<<<gather_blocks, 256, 0, stream>>>(x, cnt, elist, aggb);
    gemm_kernel<0><<<GEMM_BLOCKS, 256, 0, stream>>>(aggb, xb, INDIM, B0, br0, hA,
                                                    nullptr, nullptr, nullptr,
                                                    nullptr, nullptr, nullptr);
    // layer 1: K=256
    gather_bf16<<<gather_blocks, 256, 0, stream>>>(hA, cnt, elist, aggb);
    gemm_kernel<0><<<GEMM_BLOCKS, 256, 0, stream>>>(aggb, hA, HDIM, B1, br1, hB,
                                                    nullptr, nullptr, nullptr,
                                                    nullptr, nullptr, nullptr);
    // layer 2: K=256, fp32 outputs straight into d_out + fused head partials
    gather_bf16<<<gather_blocks, 256, 0, stream>>>(hB, cnt, elist, aggb);
    gemm_kernel<1><<<GEMM_BLOCKS, 256, 0, stream>>>(aggb, hB, HDIM, B2, br2, nullptr,
                                                    xs, x1, x2, Wsp1, Wsp2, spart);
    // head finalize
    finalize_kernel<<<(NNODES / 2 + 255) / 256, 256, 0, stream>>>(
        spart, bsp1, bsp2, Wl, bl, y);
}

// Round 3
// 607.084 us; speedup vs baseline: 1.0740x; 1.0184x over previous
//
#include <hip/hip_runtime.h>
#include <hip/hip_bf16.h>
#include <math.h>

#define NNODES 100000
#define NEDGES 400000
#define INDIM  128
#define HDIM   256
#define MAXDEG 32

// GEMM tile: BM=64 x BN=256 (full output width -> A read exactly once)
#define BM 64
#define BN 256
#define BK 64
#define MTILES 1563           // ceil(NNODES/64)

typedef __attribute__((ext_vector_type(8))) short short8;
typedef __attribute__((ext_vector_type(8))) unsigned short ushort8v;
typedef __attribute__((ext_vector_type(4))) float f32x4;

__device__ __forceinline__ float bf2f(unsigned short u) {
    union { unsigned int i; float f; } v; v.i = ((unsigned int)u) << 16; return v.f;
}
__device__ __forceinline__ unsigned short f2bf(float f) {
    union { float f; unsigned int i; } v; v.f = f;
    unsigned int r = v.i + 0x7fffu + ((v.i >> 16) & 1u);   // RNE
    return (unsigned short)(r >> 16);
}

__device__ __forceinline__ void async_load16(const void* g, void* l) {
    __builtin_amdgcn_global_load_lds(
        (const __attribute__((address_space(1))) unsigned int*)g,
        (__attribute__((address_space(3))) unsigned int*)l,
        16, 0, 0);
}

// ---------------- fused prep: convert_x + 3x convert_w + build_elist --------
#define XB_BLOCKS 12500                     // NNODES*INDIM/4 / 256
#define W0_BLOCKS 256                       // HDIM*2*INDIM / 256
#define W1_BLOCKS 512                       // HDIM*2*HDIM / 256
#define EL_BLOCKS 1563                      // ceil(NEDGES/256)
#define PREP_BLOCKS (XB_BLOCKS + W0_BLOCKS + 2 * W1_BLOCKS + EL_BLOCKS)

__global__ void prep_kernel(const float* __restrict__ x, unsigned short* __restrict__ xb,
                            const float* __restrict__ Wr0, const float* __restrict__ Ws0,
                            unsigned short* __restrict__ B0,
                            const float* __restrict__ Wr1, const float* __restrict__ Ws1,
                            unsigned short* __restrict__ B1,
                            const float* __restrict__ Wr2, const float* __restrict__ Ws2,
                            unsigned short* __restrict__ B2,
                            const int* __restrict__ ei, int* __restrict__ cnt,
                            int* __restrict__ elist) {
    int b = blockIdx.x;
    if (b < XB_BLOCKS) {
        int i = b * 256 + threadIdx.x;
        float4 v = ((const float4*)x)[i];
        ushort4 o; o.x = f2bf(v.x); o.y = f2bf(v.y); o.z = f2bf(v.z); o.w = f2bf(v.w);
        ((ushort4*)xb)[i] = o;
        return;
    }
    b -= XB_BLOCKS;
    if (b < W0_BLOCKS + 2 * W1_BLOCKS) {
        const float *Wr, *Ws; unsigned short* B; int K;
        if (b < W0_BLOCKS)               { Wr = Wr0; Ws = Ws0; B = B0; K = INDIM; }
        else if (b < W0_BLOCKS + W1_BLOCKS) { Wr = Wr1; Ws = Ws1; B = B1; K = HDIM; b -= W0_BLOCKS; }
        else                              { Wr = Wr2; Ws = Ws2; B = B2; K = HDIM; b -= W0_BLOCKS + W1_BLOCKS; }
        int idx = b * 256 + threadIdx.x;
        int n = idx / (2 * K);
        int k = idx - n * 2 * K;
        float v = (k < K) ? Wr[n * K + k] : Ws[n * K + (k - K)];
        B[idx] = f2bf(v);
        return;
    }
    b -= W0_BLOCKS + 2 * W1_BLOCKS;
    int e = b * 256 + threadIdx.x;
    if (e < NEDGES) {
        int d = ei[NEDGES + e];            // dst
        int s = ei[e];                     // src
        int pos = atomicAdd(&cnt[d], 1);
        if (pos < MAXDEG) elist[d * MAXDEG + pos] = s;
    }
}

// ---------------- gathers (bf16 rows, concurrent row loads) -----------------
__global__ void gather_bf16_128(const unsigned short* __restrict__ h, const int* __restrict__ cnt,
                                const int* __restrict__ elist, unsigned short* __restrict__ agg) {
    int wid  = (blockIdx.x * blockDim.x + threadIdx.x) >> 6;
    int lane = threadIdx.x & 63;
    if (wid >= NNODES) return;
    int c = cnt[wid]; if (c > MAXDEG) c = MAXDEG;
    const int4* el4 = (const int4*)(elist + wid * MAXDEG);
    float a0 = 0.f, a1 = 0.f;
    for (int j0 = 0; j0 < c; j0 += 4) {
        int4 e = el4[j0 >> 2];
        int rem = c - j0;
        ushort2 v0 = {0,0}, v1 = {0,0}, v2 = {0,0}, v3 = {0,0};
        v0 = ((const ushort2*)(h + (size_t)e.x * INDIM))[lane];
        if (rem > 1) v1 = ((const ushort2*)(h + (size_t)e.y * INDIM))[lane];
        if (rem > 2) v2 = ((const ushort2*)(h + (size_t)e.z * INDIM))[lane];
        if (rem > 3) v3 = ((const ushort2*)(h + (size_t)e.w * INDIM))[lane];
        a0 += bf2f(v0.x) + bf2f(v1.x) + bf2f(v2.x) + bf2f(v3.x);
        a1 += bf2f(v0.y) + bf2f(v1.y) + bf2f(v2.y) + bf2f(v3.y);
    }
    ushort2 o; o.x = f2bf(a0); o.y = f2bf(a1);
    ((ushort2*)(agg + (size_t)wid * INDIM))[lane] = o;
}

__global__ void gather_bf16_256(const unsigned short* __restrict__ h, const int* __restrict__ cnt,
                                const int* __restrict__ elist, unsigned short* __restrict__ agg) {
    int wid  = (blockIdx.x * blockDim.x + threadIdx.x) >> 6;
    int lane = threadIdx.x & 63;
    if (wid >= NNODES) return;
    int c = cnt[wid]; if (c > MAXDEG) c = MAXDEG;
    const int4* el4 = (const int4*)(elist + wid * MAXDEG);
    float a0 = 0.f, a1 = 0.f, a2 = 0.f, a3 = 0.f;
    for (int j0 = 0; j0 < c; j0 += 4) {
        int4 e = el4[j0 >> 2];
        int rem = c - j0;
        ushort4 v0 = {0,0,0,0}, v1 = {0,0,0,0}, v2 = {0,0,0,0}, v3 = {0,0,0,0};
        v0 = ((const ushort4*)(h + (size_t)e.x * HDIM))[lane];
        if (rem > 1) v1 = ((const ushort4*)(h + (size_t)e.y * HDIM))[lane];
        if (rem > 2) v2 = ((const ushort4*)(h + (size_t)e.z * HDIM))[lane];
        if (rem > 3) v3 = ((const ushort4*)(h + (size_t)e.w * HDIM))[lane];
        a0 += bf2f(v0.x) + bf2f(v1.x) + bf2f(v2.x) + bf2f(v3.x);
        a1 += bf2f(v0.y) + bf2f(v1.y) + bf2f(v2.y) + bf2f(v3.y);
        a2 += bf2f(v0.z) + bf2f(v1.z) + bf2f(v2.z) + bf2f(v3.z);
        a3 += bf2f(v0.w) + bf2f(v1.w) + bf2f(v2.w) + bf2f(v3.w);
    }
    ushort4 o; o.x = f2bf(a0); o.y = f2bf(a1); o.z = f2bf(a2); o.w = f2bf(a3);
    ((ushort4*)(agg + (size_t)wid * HDIM))[lane] = o;
}

// ---------------- fused dual-GEMM + bias + relu (+head partial in MODE 1) ---
// Tile 64x256: block covers ALL output cols -> A rows read exactly once.
// Wave w computes rows m0..m0+63 x cols w*64..w*64+63 as 4x4 MFMA tiles.
// B buffer is [n][k] over k_tot=2K (Wr then Ws).
template<int MODE>
__global__ __launch_bounds__(256)
void gemm_kernel(const unsigned short* __restrict__ A1, const unsigned short* __restrict__ A2,
                 int K, const unsigned short* __restrict__ B, const float* __restrict__ bias,
                 unsigned short* __restrict__ hout,
                 float* __restrict__ xs, float* __restrict__ x1o, float* __restrict__ x2o,
                 const float* __restrict__ Wsp1, const float* __restrict__ Wsp2,
                 float* __restrict__ spart) {
    __shared__ __align__(16) unsigned char smem[(BM * BK + BN * BK) * 2];  // 40 KB
    unsigned short* Ash = (unsigned short*)smem;
    unsigned short* Bsh = Ash + BM * BK;

    const int tid  = threadIdx.x;
    const int lane = tid & 63;
    const int wn   = tid >> 6;            // wave = output column quadrant
    const int m0   = blockIdx.x * BM;
    const int Ktot = 2 * K;

    f32x4 acc[4][4];
    for (int i = 0; i < 4; i++)
        for (int j = 0; j < 4; j++)
            acc[i][j] = (f32x4){0.f, 0.f, 0.f, 0.f};

    for (int k0 = 0; k0 < Ktot; k0 += BK) {
        const unsigned short* Abase; int koff;
        if (k0 < K) { Abase = A1; koff = k0; } else { Abase = A2; koff = k0 - K; }

        // stage A: 64 rows x 64 cols bf16 (512 x 16B segs), xor-swizzled
        #pragma unroll
        for (int it = 0; it < 2; it++) {
            int idx = it * 256 + tid;
            int row = idx >> 3, seg = idx & 7;
            int gseg = seg ^ (row & 7);
            int grow = m0 + row; if (grow >= NNODES) grow = NNODES - 1;
            async_load16(Abase + (size_t)grow * K + koff + gseg * 8, &Ash[idx * 8]);
        }
        // stage B: 256 rows x 64 cols (2048 x 16B segs)
        #pragma unroll
        for (int it = 0; it < 8; it++) {
            int idx = it * 256 + tid;
            int row = idx >> 3, seg = idx & 7;
            int gseg = seg ^ (row & 7);
            async_load16(B + (size_t)row * Ktot + k0 + gseg * 8, &Bsh[idx * 8]);
        }
        __syncthreads();

        #pragma unroll
        for (int half = 0; half < 2; half++) {
            short8 af[4], bfr[4];
            #pragma unroll
            for (int mt = 0; mt < 4; mt++) {
                int ml  = mt * 16 + (lane & 15);
                int seg = half * 4 + (lane >> 4);
                int ps  = seg ^ (ml & 7);
                af[mt] = *(const short8*)&Ash[ml * BK + ps * 8];
            }
            #pragma unroll
            for (int nt = 0; nt < 4; nt++) {
                int nl  = wn * 64 + nt * 16 + (lane & 15);
                int seg = half * 4 + (lane >> 4);
                int ps  = seg ^ (nl & 7);
                bfr[nt] = *(const short8*)&Bsh[nl * BK + ps * 8];
            }
            #pragma unroll
            for (int mt = 0; mt < 4; mt++)
                #pragma unroll
                for (int nt = 0; nt < 4; nt++)
                    acc[mt][nt] = __builtin_amdgcn_mfma_f32_16x16x32_bf16(
                        af[mt], bfr[nt], acc[mt][nt], 0, 0, 0);
        }
        __syncthreads();
    }

    // ---- epilogue via LDS bounce: wide coalesced stores ----
    // per wave: 16 rows x 64 cols fp32, row stride 68 (2-way banks = free)
    float* bounce = (float*)smem;
    float* wb = bounce + wn * (16 * 68);
    const int q    = lane & 3;       // 16-col segment in read phase
    const int rrow = lane >> 2;      // row 0..15 in read phase

    #pragma unroll
    for (int mt = 0; mt < 4; mt++) {
        __syncthreads();
        #pragma unroll
        for (int nt = 0; nt < 4; nt++)
            #pragma unroll
            for (int rr = 0; rr < 4; rr++)
                wb[((lane >> 4) * 4 + rr) * 68 + nt * 16 + (lane & 15)] = acc[mt][nt][rr];
        __syncthreads();

        int grow = m0 + mt * 16 + rrow;
        int gc   = wn * 64 + q * 16;
        float4 v[4];
        #pragma unroll
        for (int s = 0; s < 4; s++)
            v[s] = ((const float4*)(wb + rrow * 68 + q * 16))[s];

        if (grow < NNODES) {
            const float4* bv = (const float4*)(bias + gc);
            #pragma unroll
            for (int s = 0; s < 4; s++) {
                float4 b4 = bv[s];
                v[s].x = fmaxf(v[s].x + b4.x, 0.f);
                v[s].y = fmaxf(v[s].y + b4.y, 0.f);
                v[s].z = fmaxf(v[s].z + b4.z, 0.f);
                v[s].w = fmaxf(v[s].w + b4.w, 0.f);
            }
            if (MODE == 0) {
                ushort8v o0, o1;
                o0[0]=f2bf(v[0].x); o0[1]=f2bf(v[0].y); o0[2]=f2bf(v[0].z); o0[3]=f2bf(v[0].w);
                o0[4]=f2bf(v[1].x); o0[5]=f2bf(v[1].y); o0[6]=f2bf(v[1].z); o0[7]=f2bf(v[1].w);
                o1[0]=f2bf(v[2].x); o1[1]=f2bf(v[2].y); o1[2]=f2bf(v[2].z); o1[3]=f2bf(v[2].w);
                o1[4]=f2bf(v[3].x); o1[5]=f2bf(v[3].y); o1[6]=f2bf(v[3].z); o1[7]=f2bf(v[3].w);
                ushort8v* dst = (ushort8v*)(hout + (size_t)grow * HDIM + gc);
                dst[0] = o0; dst[1] = o1;
            } else {
                float4* xsp = (float4*)(xs + (size_t)grow * HDIM + gc);
                #pragma unroll
                for (int s = 0; s < 4; s++) xsp[s] = v[s];
                float* xo = (grow & 1) ? x2o : x1o;
                float4* xop = (float4*)(xo + (size_t)(grow >> 1) * HDIM + gc);
                #pragma unroll
                for (int s = 0; s < 4; s++) xop[s] = v[s];
                // head partial over this 64-col slice
                const float* wsp = (grow & 1) ? Wsp2 : Wsp1;
                const float4* wv = (const float4*)(wsp + gc);
                float p = 0.f;
                #pragma unroll
                for (int s = 0; s < 4; s++) {
                    float4 w4 = wv[s];
                    p += v[s].x * w4.x + v[s].y * w4.y + v[s].z * w4.z + v[s].w * w4.w;
                }
                p += __shfl_xor(p, 1);
                p += __shfl_xor(p, 2);
                if (q == 0) atomicAdd(&spart[grow], p);
            }
        }
    }
}

// ---------------- head finalize ---------------------------------------------
__global__ void finalize_kernel(const float* __restrict__ spart, const float* __restrict__ bsp1,
                                const float* __restrict__ bsp2, const float* __restrict__ Wl,
                                const float* __restrict__ bl, float* __restrict__ y) {
    int p = blockIdx.x * 256 + threadIdx.x;
    if (p < NNODES / 2) {
        float s1 = spart[2 * p]     + bsp1[0]; s1 = s1 > 0.f ? s1 : 0.f;
        float s2 = spart[2 * p + 1] + bsp2[0]; s2 = s2 > 0.f ? s2 : 0.f;
        float t = s1 * Wl[0] + s2 * Wl[1] + bl[0];
        y[p] = 1.f / (1.f + expf(-t));
    }
}

extern "C" void kernel_launch(void* const* d_in, const int* in_sizes, int n_in,
                              void* d_out, int out_size, void* d_ws, size_t ws_size,
                              hipStream_t stream) {
    const float* x    = (const float*)d_in[0];
    const int*   ei   = (const int*)d_in[1];
    const float* Wr0  = (const float*)d_in[3];
    const float* br0  = (const float*)d_in[4];
    const float* Ws0  = (const float*)d_in[5];
    const float* Wr1  = (const float*)d_in[6];
    const float* br1  = (const float*)d_in[7];
    const float* Ws1  = (const float*)d_in[8];
    const float* Wr2  = (const float*)d_in[9];
    const float* br2  = (const float*)d_in[10];
    const float* Ws2  = (const float*)d_in[11];
    const float* Wsp1 = (const float*)d_in[12];
    const float* bsp1 = (const float*)d_in[13];
    const float* Wsp2 = (const float*)d_in[14];
    const float* bsp2 = (const float*)d_in[15];
    const float* Wl   = (const float*)d_in[16];
    const float* bl   = (const float*)d_in[17];

    char* ws = (char*)d_ws;
    size_t off = 0;
    auto alloc = [&](size_t bytes) -> void* {
        void* p = ws + off;
        off += (bytes + 255) & ~(size_t)255;
        return p;
    };
    int*            cnt   = (int*)alloc((size_t)NNODES * 4);          // zeroed
    float*          spart = (float*)alloc((size_t)NNODES * 4);        // zeroed (adjacent)
    size_t zero_bytes = off;
    int*            elist = (int*)alloc((size_t)NNODES * MAXDEG * 4);
    unsigned short* xb    = (unsigned short*)alloc((size_t)NNODES * INDIM * 2);
    unsigned short* aggb  = (unsigned short*)alloc((size_t)NNODES * HDIM * 2);
    unsigned short* hA    = (unsigned short*)alloc((size_t)NNODES * HDIM * 2);
    unsigned short* hB    = (unsigned short*)alloc((size_t)NNODES * HDIM * 2);
    unsigned short* B0    = (unsigned short*)alloc((size_t)HDIM * 2 * INDIM * 2);
    unsigned short* B1    = (unsigned short*)alloc((size_t)HDIM * 2 * HDIM * 2);
    unsigned short* B2    = (unsigned short*)alloc((size_t)HDIM * 2 * HDIM * 2);

    // d_out layout: y (50000) | xs (50000*512) | x1 (50000*256) | x2 (50000*256)
    float* y  = (float*)d_out;
    float* xs = y + 50000;
    float* x1 = xs + (size_t)50000 * 512;
    float* x2 = x1 + (size_t)50000 * 256;

    hipMemsetAsync(ws, 0, zero_bytes, stream);   // cnt + spart
    prep_kernel<<<PREP_BLOCKS, 256, 0, stream>>>(x, xb, Wr0, Ws0, B0, Wr1, Ws1, B1,
                                                 Wr2, Ws2, B2, ei, cnt, elist);

    int gather_blocks = (NNODES * 64 + 255) / 256;

    // layer 0: gather from bf16 x (halved read traffic), K=128
    gather_bf16_128<<<gather_blocks, 256, 0, stream>>>(xb, cnt, elist, aggb);
    gemm_kernel<0><<<MTILES, 256, 0, stream>>>(aggb, xb, INDIM, B0, br0, hA,
                                               nullptr, nullptr, nullptr,
                                               nullptr, nullptr, nullptr);
    // layer 1: K=256
    gather_bf16_256<<<gather_blocks, 256, 0, stream>>>(hA, cnt, elist, aggb);
    gemm_kernel<0><<<MTILES, 256, 0, stream>>>(aggb, hA, HDIM, B1, br1, hB,
                                               nullptr, nullptr, nullptr,
                                               nullptr, nullptr, nullptr);
    // layer 2: K=256, fp32 outputs straight into d_out + fused head partials
    gather_bf16_256<<<gather_blocks, 256, 0, stream>>>(hB, cnt, elist, aggb);
    gemm_kernel<1><<<MTILES, 256, 0, stream>>>(aggb, hB, HDIM, B2, br2, nullptr,
                                               xs, x1, x2, Wsp1, Wsp2, spart);
    // head finalize
    finalize_kernel<<<(NNODES / 2 + 255) / 256, 256, 0, stream>>>(
        spart, bsp1, bsp2, Wl, bl, y);
}